// Round 6
// baseline (454.238 us; speedup 1.0000x reference)
//
#include <hip/hip_runtime.h>
#include <hip/hip_bf16.h>

#define EPS 1e-5f

constexpr int NN = 50000;   // nodes
constexpr int NE = 800000;  // edges

typedef __attribute__((ext_vector_type(8))) __bf16 bf16x8;
typedef __attribute__((ext_vector_type(4))) float f32x4;

// ---------------- utility kernels ----------------
__global__ void memset_i32(int* p, int n) {
  int i = blockIdx.x * blockDim.x + threadIdx.x;
  if (i < n) p[i] = 0;
}

__global__ void deg_kernel(const int* __restrict__ dst, int* __restrict__ degi, int n) {
  int i = blockIdx.x * blockDim.x + threadIdx.x;
  if (i < n) atomicAdd(&degi[dst[i]], 1);
}

__global__ void dinv_kernel(const int* __restrict__ degi, float* __restrict__ dinv, int n) {
  int i = blockIdx.x * blockDim.x + threadIdx.x;
  if (i < n) dinv[i] = rsqrtf((float)(degi[i] + 1));  // +1 self loop
}

// ---------------- scan (row_ptr build) ----------------
__global__ __launch_bounds__(1024) void scan1(const int* __restrict__ cnt,
                                              int* __restrict__ incl,
                                              int* __restrict__ bsum, int n) {
  __shared__ int s[1024];
  int tid = threadIdx.x;
  int i = blockIdx.x * 1024 + tid;
  int v = (i < n) ? cnt[i] : 0;
  s[tid] = v;
  __syncthreads();
  for (int off = 1; off < 1024; off <<= 1) {
    int t = (tid >= off) ? s[tid - off] : 0;
    __syncthreads();
    s[tid] += t;
    __syncthreads();
  }
  if (i < n) incl[i] = s[tid];
  if (tid == 1023) bsum[blockIdx.x] = s[1023];
}

__global__ void scan2(int* __restrict__ bsum, int nb) {
  int lane = threadIdx.x;  // single wave of 64
  int v = (lane < nb) ? bsum[lane] : 0;
  int orig = v;
  for (int off = 1; off < 64; off <<= 1) {
    int t = __shfl_up(v, off, 64);
    if (lane >= off) v += t;
  }
  if (lane < nb) bsum[lane] = v - orig;  // exclusive block offset
}

__global__ __launch_bounds__(1024) void scan3(const int* __restrict__ cnt,
                                              const int* __restrict__ incl,
                                              const int* __restrict__ bsum,
                                              int* __restrict__ rp,
                                              int* __restrict__ cursor, int n) {
  int tid = threadIdx.x;
  int i = blockIdx.x * 1024 + tid;
  if (i < n) {
    int v = incl[i] + bsum[blockIdx.x];
    rp[i + 1] = v;
    cursor[i] = v - cnt[i];
  }
  if (i == 0) rp[0] = 0;
}

// fill src-CSR: tmp_dst holds dst of each edge grouped by src
__global__ void fill_src(const int* __restrict__ src, const int* __restrict__ dst,
                         int* __restrict__ cursor_s, int* __restrict__ tmp_dst, int n) {
  int i = blockIdx.x * blockDim.x + threadIdx.x;
  if (i < n) {
    int pos = atomicAdd(&cursor_s[src[i]], 1);
    tmp_dst[pos] = dst[i];
  }
}

// fill dst-CSR by walking srcs in order -> each dst list ~sorted by src (L2 sweep locality)
__global__ void fill_dst_sorted(const int* __restrict__ rps, const int* __restrict__ tmp_dst,
                                int* __restrict__ cursor, int* __restrict__ col, int nnodes) {
  int s = blockIdx.x * blockDim.x + threadIdx.x;
  if (s >= nnodes) return;
  int p0 = rps[s], p1 = rps[s + 1];
  for (int p = p0; p < p1; p++) {
    int d = tmp_dst[p];
    int pos = atomicAdd(&cursor[d], 1);
    col[pos] = s;
  }
}

// ---------------- weight transpose + split into bf16 hi/lo [N][K] ----------------
__global__ void wsplit(const float* __restrict__ W, __bf16* __restrict__ th,
                       __bf16* __restrict__ tl, int K, int N) {
  int i = blockIdx.x * blockDim.x + threadIdx.x;
  if (i >= K * N) return;
  int k = i / N, n = i - k * N;
  float v = W[i];
  __bf16 h = (__bf16)v;
  th[(size_t)n * K + k] = h;
  tl[(size_t)n * K + k] = (__bf16)(v - (float)h);
}

// ---------------- propagation (pull over CSR), predicated batched gathers ----------------
// One wave per node. Always issue D gathers (clamped index, weight 0 for tail slots)
// -> no serial tail, D rows outstanding per wave.
// EPI: 0 = dinv only; 1 = dinv + bias + BN + ReLU; 2 = dinv + bias
// SPLIT: write bf16 hi/lo planes. PRESCALE: multiply gathered rows by dinv[src]
template <int F, int EPI, bool SPLIT, bool PRESCALE>
__global__ __launch_bounds__(256, 8) void prop_kernel(
    const float* __restrict__ in, const int* __restrict__ rp, const int* __restrict__ col,
    const float* __restrict__ dinv, const float* __restrict__ bias,
    const float* __restrict__ gam, const float* __restrict__ bet,
    const float* __restrict__ mean, const float* __restrict__ var,
    float* __restrict__ out, __bf16* __restrict__ out_hi, __bf16* __restrict__ out_lo,
    int nnodes) {
  int tid = threadIdx.x;
  int wid = tid >> 6, lane = tid & 63;
  if constexpr (F >= 64) {
    constexpr int VEC = F / 64;           // floats per lane: 2 for F=128, 1 for F=64
    constexpr int D = (VEC == 2) ? 8 : 12;  // gathers in flight per wave
    typedef float fvec __attribute__((ext_vector_type(VEC)));
    typedef __bf16 bvec __attribute__((ext_vector_type(VEC)));
    int v = blockIdx.x * 4 + wid;
    if (v >= nnodes) return;
    int e0 = rp[v], e1 = rp[v + 1];
    fvec acc = *((const fvec*)(in + (size_t)v * F) + lane);  // self-loop term
    if constexpr (PRESCALE) acc *= dinv[v];
    int e1m1 = e1 - 1;
    for (int e = e0; e < e1; e += D) {
      int ss[D];
      float w[D];
      if (e + D <= e1) {  // full batch (wave-uniform branch)
#pragma unroll
        for (int u = 0; u < D; u++) ss[u] = col[e + u];
#pragma unroll
        for (int u = 0; u < D; u++) w[u] = PRESCALE ? dinv[ss[u]] : 1.0f;
      } else {            // clamped + predicated tail batch
#pragma unroll
        for (int u = 0; u < D; u++) {
          int ei = e + u;
          ss[u] = col[ei < e1m1 ? ei : e1m1];
          w[u] = (ei < e1) ? (PRESCALE ? dinv[ss[u]] : 1.0f) : 0.0f;
        }
      }
      fvec vv[D];
#pragma unroll
      for (int u = 0; u < D; u++) vv[u] = *((const fvec*)(in + (size_t)ss[u] * F) + lane);
#pragma unroll
      for (int u = 0; u < D; u++) acc += vv[u] * w[u];
    }
    float dv = dinv[v];
    if constexpr (SPLIT) {
      bvec hv, lv;
#pragma unroll
      for (int j = 0; j < VEC; j++) {
        int f = lane * VEC + j;
        float t = acc[j] * dv;
        if constexpr (EPI >= 1) t += bias[f];
        if constexpr (EPI == 1) {
          t = (t - mean[f]) * rsqrtf(var[f] + EPS) * gam[f] + bet[f];
          t = fmaxf(t, 0.f);
        }
        __bf16 h = (__bf16)t;
        hv[j] = h;
        lv[j] = (__bf16)(t - (float)h);
      }
      *((bvec*)(out_hi + (size_t)v * F) + lane) = hv;
      *((bvec*)(out_lo + (size_t)v * F) + lane) = lv;
    } else {
#pragma unroll
      for (int j = 0; j < VEC; j++) {
        int f = lane * VEC + j;
        float t = acc[j] * dv;
        if constexpr (EPI >= 1) t += bias[f];
        if constexpr (EPI == 1) {
          t = (t - mean[f]) * rsqrtf(var[f] + EPS) * gam[f] + bet[f];
          t = fmaxf(t, 0.f);
        }
        out[(size_t)v * F + f] = t;
      }
    }
  } else {
    // small F (=6): 8 lanes per node
    int g = lane >> 3, f = lane & 7;
    int v = (blockIdx.x * 4 + wid) * 8 + g;
    if (v >= nnodes || f >= F) return;
    int e0 = rp[v], e1 = rp[v + 1];
    float acc = in[(size_t)v * F + f];
    int e1m1 = e1 - 1;
    constexpr int D = 8;
    for (int e = e0; e < e1; e += D) {
      int ss[D];
      float w[D];
#pragma unroll
      for (int u = 0; u < D; u++) {
        int ei = e + u;
        ss[u] = col[ei < e1m1 ? ei : e1m1];
        w[u] = (ei < e1) ? 1.0f : 0.0f;
      }
#pragma unroll
      for (int u = 0; u < D; u++) acc = fmaf(in[(size_t)ss[u] * F + f], w[u], acc);
    }
    float t = acc * dinv[v];
    if constexpr (EPI >= 1) t += bias[f];
    if constexpr (EPI == 1) {
      t = (t - mean[f]) * rsqrtf(var[f] + EPS) * gam[f] + bet[f];
      t = fmaxf(t, 0.f);
    }
    out[(size_t)v * F + f] = t;
  }
}

// ---------------- MFMA GEMM (bf16 split-3), 128xBN tile, 4 waves ----------------
// A as hi/lo planes [M][K]; B as transposed hi/lo planes [N][K].
// EPI 0: +bias, BN, ReLU -> write hi/lo planes. EPI 1: *dinv[row] -> write f32.
template <int BN, int EPI>
__global__ __launch_bounds__(256) void mfma_gemm(
    const __bf16* __restrict__ Ahi, const __bf16* __restrict__ Alo,
    const __bf16* __restrict__ Bhi, const __bf16* __restrict__ Blo,
    const float* __restrict__ bias, const float* __restrict__ gam,
    const float* __restrict__ bet, const float* __restrict__ mean,
    const float* __restrict__ var, const float* __restrict__ dinv,
    float* __restrict__ Cf, __bf16* __restrict__ Chi, __bf16* __restrict__ Clo,
    int M, int K, int N) {
  constexpr int BM = 128, BK = 32, NB = BN / 16;
  // +8 bf16 pad (16 B): row stride 80 B spreads b128 frag reads across all 32 banks
  __shared__ __bf16 Ah[BM][BK + 8], Al[BM][BK + 8];
  __shared__ __bf16 Bh[BN][BK + 8], Bl[BN][BK + 8];
  int tid = threadIdx.x;
  int wid = tid >> 6, lane = tid & 63;
  int lr = lane & 15, lg = lane >> 4;
  int bm = blockIdx.x * BM, bn = blockIdx.y * BN;
  f32x4 acc[2][NB] = {};
  for (int k0 = 0; k0 < K; k0 += BK) {
#pragma unroll
    for (int c = 0; c < 2; c++) {  // A tile: 128 rows x 32 bf16, 16B chunks
      int idx = tid + c * 256;
      int r = idx >> 2, s = idx & 3;
      int rg = bm + r;
      uint4 vh = {0, 0, 0, 0}, vl = {0, 0, 0, 0};
      if (rg < M) {
        size_t go = (size_t)rg * K + k0 + s * 8;
        vh = *reinterpret_cast<const uint4*>(Ahi + go);
        vl = *reinterpret_cast<const uint4*>(Alo + go);
      }
      *reinterpret_cast<uint4*>(&Ah[r][s * 8]) = vh;
      *reinterpret_cast<uint4*>(&Al[r][s * 8]) = vl;
    }
    if (tid < BN * 4) {  // B tile: BN rows x 32 bf16
      int r = tid >> 2, s = tid & 3;
      int rg = bn + r;
      uint4 vh = {0, 0, 0, 0}, vl = {0, 0, 0, 0};
      if (rg < N) {
        size_t go = (size_t)rg * K + k0 + s * 8;
        vh = *reinterpret_cast<const uint4*>(Bhi + go);
        vl = *reinterpret_cast<const uint4*>(Blo + go);
      }
      *reinterpret_cast<uint4*>(&Bh[r][s * 8]) = vh;
      *reinterpret_cast<uint4*>(&Bl[r][s * 8]) = vl;
    }
    __syncthreads();
    int ar = wid * 32 + lr;
    bf16x8 ah0 = *reinterpret_cast<const bf16x8*>(&Ah[ar][lg * 8]);
    bf16x8 ah1 = *reinterpret_cast<const bf16x8*>(&Ah[ar + 16][lg * 8]);
    bf16x8 al0 = *reinterpret_cast<const bf16x8*>(&Al[ar][lg * 8]);
    bf16x8 al1 = *reinterpret_cast<const bf16x8*>(&Al[ar + 16][lg * 8]);
#pragma unroll
    for (int n = 0; n < NB; n++) {
      bf16x8 bh = *reinterpret_cast<const bf16x8*>(&Bh[n * 16 + lr][lg * 8]);
      bf16x8 bl = *reinterpret_cast<const bf16x8*>(&Bl[n * 16 + lr][lg * 8]);
      acc[0][n] = __builtin_amdgcn_mfma_f32_16x16x32_bf16(ah0, bh, acc[0][n], 0, 0, 0);
      acc[1][n] = __builtin_amdgcn_mfma_f32_16x16x32_bf16(ah1, bh, acc[1][n], 0, 0, 0);
      acc[0][n] = __builtin_amdgcn_mfma_f32_16x16x32_bf16(ah0, bl, acc[0][n], 0, 0, 0);
      acc[1][n] = __builtin_amdgcn_mfma_f32_16x16x32_bf16(ah1, bl, acc[1][n], 0, 0, 0);
      acc[0][n] = __builtin_amdgcn_mfma_f32_16x16x32_bf16(al0, bh, acc[0][n], 0, 0, 0);
      acc[1][n] = __builtin_amdgcn_mfma_f32_16x16x32_bf16(al1, bh, acc[1][n], 0, 0, 0);
    }
    __syncthreads();
  }
  // epilogue: C/D layout col=lane&15, row=(lane>>4)*4+reg (m89-verified)
#pragma unroll
  for (int m = 0; m < 2; m++) {
    int row0 = bm + wid * 32 + m * 16 + lg * 4;
#pragma unroll
    for (int n = 0; n < NB; n++) {
      int colg = bn + n * 16 + lr;
#pragma unroll
      for (int r = 0; r < 4; r++) {
        int row = row0 + r;
        if (row >= M) continue;
        float t = acc[m][n][r];
        if constexpr (EPI == 0) {
          t += bias[colg];
          t = (t - mean[colg]) * rsqrtf(var[colg] + EPS) * gam[colg] + bet[colg];
          t = fmaxf(t, 0.f);
          __bf16 h = (__bf16)t;
          Chi[(size_t)row * N + colg] = h;
          Clo[(size_t)row * N + colg] = (__bf16)(t - (float)h);
        } else {
          if (colg < N) Cf[(size_t)row * N + colg] = t * dinv[row];
        }
      }
    }
  }
}

// ---------------- launch ----------------
extern "C" void kernel_launch(void* const* d_in, const int* in_sizes, int n_in,
                              void* d_out, int out_size, void* d_ws, size_t ws_size,
                              hipStream_t stream) {
  const float* x = (const float*)d_in[0];
  const int* ei = (const int*)d_in[1];
  const int* esrc = ei;
  const int* edst = ei + NE;
  const float* W1 = (const float*)d_in[2];  const float* b1 = (const float*)d_in[3];
  const float* g1 = (const float*)d_in[4];  const float* be1 = (const float*)d_in[5];
  const float* m1 = (const float*)d_in[6];  const float* v1 = (const float*)d_in[7];
  const float* W2 = (const float*)d_in[8];  const float* b2 = (const float*)d_in[9];
  const float* g2 = (const float*)d_in[10]; const float* be2 = (const float*)d_in[11];
  const float* m2 = (const float*)d_in[12]; const float* v2 = (const float*)d_in[13];
  const float* W3 = (const float*)d_in[14]; const float* b3 = (const float*)d_in[15];
  const float* g3 = (const float*)d_in[16]; const float* be3 = (const float*)d_in[17];
  const float* m3 = (const float*)d_in[18]; const float* v3 = (const float*)d_in[19];
  const float* W4 = (const float*)d_in[20]; const float* b4 = (const float*)d_in[21];
  float* out = (float*)d_out;

  // workspace layout
  char* base = (char*)d_ws;
  size_t off = 0;
  auto alloc = [&](size_t bytes) {
    void* p = base + off;
    off = (off + bytes + 255) & ~(size_t)255;
    return p;
  };
  float* F1 = (float*)alloc((size_t)NN * 128 * 4);        // f32 activations (max 128 cols)
  __bf16* PAh = (__bf16*)alloc((size_t)NN * 128 * 2);     // A planes (<=128 cols)
  __bf16* PAl = (__bf16*)alloc((size_t)NN * 128 * 2);
  __bf16* PHh = (__bf16*)alloc((size_t)NN * 256 * 2);     // h planes (<=256 cols)
  __bf16* PHl = (__bf16*)alloc((size_t)NN * 256 * 2);
  __bf16* Wt1h = (__bf16*)alloc(128 * 256 * 2); __bf16* Wt1l = (__bf16*)alloc(128 * 256 * 2);
  __bf16* Wt2h = (__bf16*)alloc(256 * 128 * 2); __bf16* Wt2l = (__bf16*)alloc(256 * 128 * 2);
  __bf16* Wt3h = (__bf16*)alloc(128 * 64 * 2);  __bf16* Wt3l = (__bf16*)alloc(128 * 64 * 2);
  __bf16* Wt4h = (__bf16*)alloc(64 * 6 * 2);    __bf16* Wt4l = (__bf16*)alloc(64 * 6 * 2);
  int* degi = (int*)alloc((size_t)NN * 4);
  float* dinv = (float*)alloc((size_t)NN * 4);
  int* rp = (int*)alloc((size_t)(NN + 1) * 4);
  int* cursor = (int*)alloc((size_t)NN * 4);
  int* incl = (int*)alloc((size_t)NN * 4);
  int* bsum = (int*)alloc(64 * 4);
  int* col = (int*)alloc((size_t)NE * 4);
  int* cnts = (int*)alloc((size_t)NN * 4);      // src-CSR counts
  int* rps = (int*)alloc((size_t)(NN + 1) * 4); // src-CSR row ptr
  int* cursor_s = (int*)alloc((size_t)NN * 4);
  int* tmp_dst = (int*)alloc((size_t)NE * 4);

  const int nBlkN = (NN + 255) / 256;
  const int nBlkE = (NE + 255) / 256;
  const int nBlkScan = (NN + 1023) / 1024;  // 49
  const int gM = (NN + 127) / 128;          // 391

  // degree (by dst) + dinv
  memset_i32<<<nBlkN, 256, 0, stream>>>(degi, NN);
  deg_kernel<<<nBlkE, 256, 0, stream>>>(edst, degi, NE);
  dinv_kernel<<<nBlkN, 256, 0, stream>>>(degi, dinv, NN);

  // dst-CSR row ptr
  scan1<<<nBlkScan, 1024, 0, stream>>>(degi, incl, bsum, NN);
  scan2<<<1, 64, 0, stream>>>(bsum, nBlkScan);
  scan3<<<nBlkScan, 1024, 0, stream>>>(degi, incl, bsum, rp, cursor, NN);

  // src-CSR (for src-sorted fill)
  memset_i32<<<nBlkN, 256, 0, stream>>>(cnts, NN);
  deg_kernel<<<nBlkE, 256, 0, stream>>>(esrc, cnts, NE);
  scan1<<<nBlkScan, 1024, 0, stream>>>(cnts, incl, bsum, NN);
  scan2<<<1, 64, 0, stream>>>(bsum, nBlkScan);
  scan3<<<nBlkScan, 1024, 0, stream>>>(cnts, incl, bsum, rps, cursor_s, NN);
  fill_src<<<nBlkE, 256, 0, stream>>>(esrc, edst, cursor_s, tmp_dst, NE);
  fill_dst_sorted<<<nBlkN, 256, 0, stream>>>(rps, tmp_dst, cursor, col, NN);

  // weight transpose+split
  wsplit<<<(128 * 256 + 255) / 256, 256, 0, stream>>>(W1, Wt1h, Wt1l, 128, 256);
  wsplit<<<(256 * 128 + 255) / 256, 256, 0, stream>>>(W2, Wt2h, Wt2l, 256, 128);
  wsplit<<<(128 * 64 + 255) / 256, 256, 0, stream>>>(W3, Wt3h, Wt3l, 128, 64);
  wsplit<<<(64 * 6 + 255) / 256, 256, 0, stream>>>(W4, Wt4h, Wt4l, 64, 6);

  // ---- layer 1: propagate (dim 128, prescale fused) then GEMM1(+b1,BN1,ReLU -> hi/lo) ----
  prop_kernel<128, 0, true, true><<<(NN + 3) / 4, 256, 0, stream>>>(
      x, rp, col, dinv, nullptr, nullptr, nullptr, nullptr, nullptr,
      nullptr, PAh, PAl, NN);
  {
    dim3 g(gM, 4);
    mfma_gemm<64, 0><<<g, 256, 0, stream>>>(PAh, PAl, Wt1h, Wt1l, b1, g1, be1, m1, v1,
                                            nullptr, nullptr, PHh, PHl, NN, 128, 256);
  }
  // ---- layer 2: GEMM2(*dinv -> f32) then propagate(+b2,BN2,ReLU -> hi/lo) ----
  {
    dim3 g(gM, 2);
    mfma_gemm<64, 1><<<g, 256, 0, stream>>>(PHh, PHl, Wt2h, Wt2l, nullptr, nullptr, nullptr,
                                            nullptr, nullptr, dinv, F1, nullptr, nullptr,
                                            NN, 256, 128);
  }
  prop_kernel<128, 1, true, false><<<(NN + 3) / 4, 256, 0, stream>>>(
      F1, rp, col, dinv, b2, g2, be2, m2, v2, nullptr, PAh, PAl, NN);
  // ---- layer 3: GEMM3(*dinv -> f32) then propagate(+b3,BN3,ReLU -> hi/lo) ----
  {
    dim3 g(gM, 1);
    mfma_gemm<64, 1><<<g, 256, 0, stream>>>(PAh, PAl, Wt3h, Wt3l, nullptr, nullptr, nullptr,
                                            nullptr, nullptr, dinv, F1, nullptr, nullptr,
                                            NN, 128, 64);
  }
  prop_kernel<64, 1, true, false><<<(NN + 3) / 4, 256, 0, stream>>>(
      F1, rp, col, dinv, b3, g3, be3, m3, v3, nullptr, PHh, PHl, NN);
  // ---- layer 4: GEMM4(*dinv -> f32, N=6) then propagate(+b4) ----
  {
    dim3 g(gM, 1);
    mfma_gemm<16, 1><<<g, 256, 0, stream>>>(PHh, PHl, Wt4h, Wt4l, nullptr, nullptr, nullptr,
                                            nullptr, nullptr, dinv, F1, nullptr, nullptr,
                                            NN, 64, 6);
  }
  prop_kernel<6, 2, false, false><<<(NN + 31) / 32, 256, 0, stream>>>(
      F1, rp, col, dinv, b4, nullptr, nullptr, nullptr, nullptr, out, nullptr, nullptr, NN);
}

// Round 7
// 353.972 us; speedup vs baseline: 1.2833x; 1.2833x over previous
//
#include <hip/hip_runtime.h>
#include <hip/hip_bf16.h>

#define EPS 1e-5f

constexpr int NN = 50000;   // nodes
constexpr int NE = 800000;  // edges

typedef __attribute__((ext_vector_type(8))) __bf16 bf16x8;
typedef __attribute__((ext_vector_type(4))) float f32x4;

// ---------------- utility kernels ----------------
__global__ void memset_i32(int* p, int n) {
  int i = blockIdx.x * blockDim.x + threadIdx.x;
  if (i < n) p[i] = 0;
}

__global__ void deg_kernel(const int* __restrict__ dst, int* __restrict__ degi, int n) {
  int i = blockIdx.x * blockDim.x + threadIdx.x;
  if (i < n) atomicAdd(&degi[dst[i]], 1);
}

__global__ void dinv_kernel(const int* __restrict__ degi, float* __restrict__ dinv, int n) {
  int i = blockIdx.x * blockDim.x + threadIdx.x;
  if (i < n) dinv[i] = rsqrtf((float)(degi[i] + 1));  // +1 self loop
}

// ---------------- scan (row_ptr build) ----------------
__global__ __launch_bounds__(1024) void scan1(const int* __restrict__ cnt,
                                              int* __restrict__ incl,
                                              int* __restrict__ bsum, int n) {
  __shared__ int s[1024];
  int tid = threadIdx.x;
  int i = blockIdx.x * 1024 + tid;
  int v = (i < n) ? cnt[i] : 0;
  s[tid] = v;
  __syncthreads();
  for (int off = 1; off < 1024; off <<= 1) {
    int t = (tid >= off) ? s[tid - off] : 0;
    __syncthreads();
    s[tid] += t;
    __syncthreads();
  }
  if (i < n) incl[i] = s[tid];
  if (tid == 1023) bsum[blockIdx.x] = s[1023];
}

__global__ void scan2(int* __restrict__ bsum, int nb) {
  int lane = threadIdx.x;  // single wave of 64
  int v = (lane < nb) ? bsum[lane] : 0;
  int orig = v;
  for (int off = 1; off < 64; off <<= 1) {
    int t = __shfl_up(v, off, 64);
    if (lane >= off) v += t;
  }
  if (lane < nb) bsum[lane] = v - orig;  // exclusive block offset
}

__global__ __launch_bounds__(1024) void scan3(const int* __restrict__ cnt,
                                              const int* __restrict__ incl,
                                              const int* __restrict__ bsum,
                                              int* __restrict__ rp,
                                              int* __restrict__ cursor, int n) {
  int tid = threadIdx.x;
  int i = blockIdx.x * 1024 + tid;
  if (i < n) {
    int v = incl[i] + bsum[blockIdx.x];
    rp[i + 1] = v;
    cursor[i] = v - cnt[i];
  }
  if (i == 0) rp[0] = 0;
}

__global__ void fill_kernel(const int* __restrict__ src, const int* __restrict__ dst,
                            int* __restrict__ cursor, int* __restrict__ col, int n) {
  int i = blockIdx.x * blockDim.x + threadIdx.x;
  if (i < n) {
    int pos = atomicAdd(&cursor[dst[i]], 1);
    col[pos] = src[i];
  }
}

// ---------------- weight transpose + split into bf16 hi/lo [N][K] ----------------
__global__ void wsplit(const float* __restrict__ W, __bf16* __restrict__ th,
                       __bf16* __restrict__ tl, int K, int N) {
  int i = blockIdx.x * blockDim.x + threadIdx.x;
  if (i >= K * N) return;
  int k = i / N, n = i - k * N;
  float v = W[i];
  __bf16 h = (__bf16)v;
  th[(size_t)n * K + k] = h;
  tl[(size_t)n * K + k] = (__bf16)(v - (float)h);
}

// ---------------- propagation (pull over CSR), predicated batched gathers ----------------
// One wave per node. Always issue D gathers (clamped index; tail contributions
// zeroed) -> no serial tail, D rows outstanding per wave.
// PRESCALE variant: D=8 with dinv[src] weight gathers (control arm).
// Non-prescale: D=16, tail handled by select-to-zero on the gathered value.
// EPI: 0 = dinv only; 1 = dinv + bias + BN + ReLU; 2 = dinv + bias
// SPLIT: write bf16 hi/lo planes instead of f32.
template <int F, int EPI, bool SPLIT, bool PRESCALE>
__global__ __launch_bounds__(256, PRESCALE ? 8 : 6) void prop_kernel(
    const float* __restrict__ in, const int* __restrict__ rp, const int* __restrict__ col,
    const float* __restrict__ dinv, const float* __restrict__ bias,
    const float* __restrict__ gam, const float* __restrict__ bet,
    const float* __restrict__ mean, const float* __restrict__ var,
    float* __restrict__ out, __bf16* __restrict__ out_hi, __bf16* __restrict__ out_lo,
    int nnodes) {
  int tid = threadIdx.x;
  int wid = tid >> 6, lane = tid & 63;
  if constexpr (F >= 64) {
    constexpr int VEC = F / 64;             // floats per lane: 2 for F=128, 1 for F=64
    constexpr int D = PRESCALE ? 8 : 16;    // gathers in flight per wave
    typedef float fvec __attribute__((ext_vector_type(VEC)));
    typedef __bf16 bvec __attribute__((ext_vector_type(VEC)));
    int v = blockIdx.x * 4 + wid;
    if (v >= nnodes) return;
    int e0 = rp[v], e1 = rp[v + 1];
    fvec acc = *((const fvec*)(in + (size_t)v * F) + lane);  // self-loop term
    if constexpr (PRESCALE) acc *= dinv[v];
    int e1m1 = e1 - 1;
    for (int e = e0; e < e1; e += D) {
      int ss[D];
      bool full = (e + D <= e1);
      if (full) {
#pragma unroll
        for (int u = 0; u < D; u++) ss[u] = col[e + u];
      } else {
#pragma unroll
        for (int u = 0; u < D; u++) {
          int ei = e + u;
          ss[u] = col[ei < e1m1 ? ei : e1m1];
        }
      }
      fvec vv[D];
#pragma unroll
      for (int u = 0; u < D; u++) vv[u] = *((const fvec*)(in + (size_t)ss[u] * F) + lane);
      if constexpr (PRESCALE) {
        float w[D];
#pragma unroll
        for (int u = 0; u < D; u++)
          w[u] = (full || (e + u < e1)) ? dinv[ss[u]] : 0.0f;
#pragma unroll
        for (int u = 0; u < D; u++) acc += vv[u] * w[u];
      } else {
        if (full) {
#pragma unroll
          for (int u = 0; u < D; u++) acc += vv[u];
        } else {
#pragma unroll
          for (int u = 0; u < D; u++)
            if (e + u < e1) acc += vv[u];
        }
      }
    }
    float dv = dinv[v];
    if constexpr (SPLIT) {
      bvec hv, lv;
#pragma unroll
      for (int j = 0; j < VEC; j++) {
        int f = lane * VEC + j;
        float t = acc[j] * dv;
        if constexpr (EPI >= 1) t += bias[f];
        if constexpr (EPI == 1) {
          t = (t - mean[f]) * rsqrtf(var[f] + EPS) * gam[f] + bet[f];
          t = fmaxf(t, 0.f);
        }
        __bf16 h = (__bf16)t;
        hv[j] = h;
        lv[j] = (__bf16)(t - (float)h);
      }
      *((bvec*)(out_hi + (size_t)v * F) + lane) = hv;
      *((bvec*)(out_lo + (size_t)v * F) + lane) = lv;
    } else {
#pragma unroll
      for (int j = 0; j < VEC; j++) {
        int f = lane * VEC + j;
        float t = acc[j] * dv;
        if constexpr (EPI >= 1) t += bias[f];
        if constexpr (EPI == 1) {
          t = (t - mean[f]) * rsqrtf(var[f] + EPS) * gam[f] + bet[f];
          t = fmaxf(t, 0.f);
        }
        out[(size_t)v * F + f] = t;
      }
    }
  } else {
    // small F (=6): 8 lanes per node
    int g = lane >> 3, f = lane & 7;
    int v = (blockIdx.x * 4 + wid) * 8 + g;
    if (v >= nnodes || f >= F) return;
    int e0 = rp[v], e1 = rp[v + 1];
    float acc = in[(size_t)v * F + f];
    int e1m1 = e1 - 1;
    constexpr int D = 8;
    for (int e = e0; e < e1; e += D) {
      int ss[D];
      float w[D];
#pragma unroll
      for (int u = 0; u < D; u++) {
        int ei = e + u;
        ss[u] = col[ei < e1m1 ? ei : e1m1];
        w[u] = (ei < e1) ? 1.0f : 0.0f;
      }
#pragma unroll
      for (int u = 0; u < D; u++) acc = fmaf(in[(size_t)ss[u] * F + f], w[u], acc);
    }
    float t = acc * dinv[v];
    if constexpr (EPI >= 1) t += bias[f];
    if constexpr (EPI == 1) {
      t = (t - mean[f]) * rsqrtf(var[f] + EPS) * gam[f] + bet[f];
      t = fmaxf(t, 0.f);
    }
    out[(size_t)v * F + f] = t;
  }
}

// ---------------- MFMA GEMM (bf16 split-3), 128xBN tile, 4 waves ----------------
// A as hi/lo planes [M][K]; B as transposed hi/lo planes [N][K].
// EPI 0: +bias, BN, ReLU -> write hi/lo planes. EPI 1: *dinv[row] -> write f32.
template <int BN, int EPI>
__global__ __launch_bounds__(256, 4) void mfma_gemm(
    const __bf16* __restrict__ Ahi, const __bf16* __restrict__ Alo,
    const __bf16* __restrict__ Bhi, const __bf16* __restrict__ Blo,
    const float* __restrict__ bias, const float* __restrict__ gam,
    const float* __restrict__ bet, const float* __restrict__ mean,
    const float* __restrict__ var, const float* __restrict__ dinv,
    float* __restrict__ Cf, __bf16* __restrict__ Chi, __bf16* __restrict__ Clo,
    int M, int K, int N) {
  constexpr int BM = 128, BK = 32, NB = BN / 16;
  // +8 bf16 pad (16 B): row stride 80 B spreads b128 frag reads across all 32 banks
  __shared__ __bf16 Ah[BM][BK + 8], Al[BM][BK + 8];
  __shared__ __bf16 Bh[BN][BK + 8], Bl[BN][BK + 8];
  int tid = threadIdx.x;
  int wid = tid >> 6, lane = tid & 63;
  int lr = lane & 15, lg = lane >> 4;
  int bm = blockIdx.x * BM, bn = blockIdx.y * BN;
  f32x4 acc[2][NB] = {};
  for (int k0 = 0; k0 < K; k0 += BK) {
#pragma unroll
    for (int c = 0; c < 2; c++) {  // A tile: 128 rows x 32 bf16, 16B chunks
      int idx = tid + c * 256;
      int r = idx >> 2, s = idx & 3;
      int rg = bm + r;
      uint4 vh = {0, 0, 0, 0}, vl = {0, 0, 0, 0};
      if (rg < M) {
        size_t go = (size_t)rg * K + k0 + s * 8;
        vh = *reinterpret_cast<const uint4*>(Ahi + go);
        vl = *reinterpret_cast<const uint4*>(Alo + go);
      }
      *reinterpret_cast<uint4*>(&Ah[r][s * 8]) = vh;
      *reinterpret_cast<uint4*>(&Al[r][s * 8]) = vl;
    }
#pragma unroll
    for (int c = 0; c < (BN * 4 + 255) / 256; c++) {  // B tile: BN rows x 32 bf16
      int idx = tid + c * 256;
      if (idx < BN * 4) {
        int r = idx >> 2, s = idx & 3;
        int rg = bn + r;
        uint4 vh = {0, 0, 0, 0}, vl = {0, 0, 0, 0};
        if (rg < N) {
          size_t go = (size_t)rg * K + k0 + s * 8;
          vh = *reinterpret_cast<const uint4*>(Bhi + go);
          vl = *reinterpret_cast<const uint4*>(Blo + go);
        }
        *reinterpret_cast<uint4*>(&Bh[r][s * 8]) = vh;
        *reinterpret_cast<uint4*>(&Bl[r][s * 8]) = vl;
      }
    }
    __syncthreads();
    int ar = wid * 32 + lr;
    bf16x8 ah0 = *reinterpret_cast<const bf16x8*>(&Ah[ar][lg * 8]);
    bf16x8 ah1 = *reinterpret_cast<const bf16x8*>(&Ah[ar + 16][lg * 8]);
    bf16x8 al0 = *reinterpret_cast<const bf16x8*>(&Al[ar][lg * 8]);
    bf16x8 al1 = *reinterpret_cast<const bf16x8*>(&Al[ar + 16][lg * 8]);
#pragma unroll
    for (int n = 0; n < NB; n++) {
      bf16x8 bh = *reinterpret_cast<const bf16x8*>(&Bh[n * 16 + lr][lg * 8]);
      bf16x8 bl = *reinterpret_cast<const bf16x8*>(&Bl[n * 16 + lr][lg * 8]);
      acc[0][n] = __builtin_amdgcn_mfma_f32_16x16x32_bf16(ah0, bh, acc[0][n], 0, 0, 0);
      acc[1][n] = __builtin_amdgcn_mfma_f32_16x16x32_bf16(ah1, bh, acc[1][n], 0, 0, 0);
      acc[0][n] = __builtin_amdgcn_mfma_f32_16x16x32_bf16(ah0, bl, acc[0][n], 0, 0, 0);
      acc[1][n] = __builtin_amdgcn_mfma_f32_16x16x32_bf16(ah1, bl, acc[1][n], 0, 0, 0);
      acc[0][n] = __builtin_amdgcn_mfma_f32_16x16x32_bf16(al0, bh, acc[0][n], 0, 0, 0);
      acc[1][n] = __builtin_amdgcn_mfma_f32_16x16x32_bf16(al1, bh, acc[1][n], 0, 0, 0);
    }
    __syncthreads();
  }
  // epilogue: C/D layout col=lane&15, row=(lane>>4)*4+reg (m89-verified)
#pragma unroll
  for (int m = 0; m < 2; m++) {
    int row0 = bm + wid * 32 + m * 16 + lg * 4;
#pragma unroll
    for (int n = 0; n < NB; n++) {
      int colg = bn + n * 16 + lr;
#pragma unroll
      for (int r = 0; r < 4; r++) {
        int row = row0 + r;
        if (row >= M) continue;
        float t = acc[m][n][r];
        if constexpr (EPI == 0) {
          t += bias[colg];
          t = (t - mean[colg]) * rsqrtf(var[colg] + EPS) * gam[colg] + bet[colg];
          t = fmaxf(t, 0.f);
          __bf16 h = (__bf16)t;
          Chi[(size_t)row * N + colg] = h;
          Clo[(size_t)row * N + colg] = (__bf16)(t - (float)h);
        } else {
          if (colg < N) Cf[(size_t)row * N + colg] = t * dinv[row];
        }
      }
    }
  }
}

// ---------------- launch ----------------
extern "C" void kernel_launch(void* const* d_in, const int* in_sizes, int n_in,
                              void* d_out, int out_size, void* d_ws, size_t ws_size,
                              hipStream_t stream) {
  const float* x = (const float*)d_in[0];
  const int* ei = (const int*)d_in[1];
  const int* esrc = ei;
  const int* edst = ei + NE;
  const float* W1 = (const float*)d_in[2];  const float* b1 = (const float*)d_in[3];
  const float* g1 = (const float*)d_in[4];  const float* be1 = (const float*)d_in[5];
  const float* m1 = (const float*)d_in[6];  const float* v1 = (const float*)d_in[7];
  const float* W2 = (const float*)d_in[8];  const float* b2 = (const float*)d_in[9];
  const float* g2 = (const float*)d_in[10]; const float* be2 = (const float*)d_in[11];
  const float* m2 = (const float*)d_in[12]; const float* v2 = (const float*)d_in[13];
  const float* W3 = (const float*)d_in[14]; const float* b3 = (const float*)d_in[15];
  const float* g3 = (const float*)d_in[16]; const float* be3 = (const float*)d_in[17];
  const float* m3 = (const float*)d_in[18]; const float* v3 = (const float*)d_in[19];
  const float* W4 = (const float*)d_in[20]; const float* b4 = (const float*)d_in[21];
  float* out = (float*)d_out;

  // workspace layout
  char* base = (char*)d_ws;
  size_t off = 0;
  auto alloc = [&](size_t bytes) {
    void* p = base + off;
    off = (off + bytes + 255) & ~(size_t)255;
    return p;
  };
  float* F1 = (float*)alloc((size_t)NN * 128 * 4);        // f32 activations (max 128 cols)
  __bf16* PAh = (__bf16*)alloc((size_t)NN * 128 * 2);     // A planes (<=128 cols)
  __bf16* PAl = (__bf16*)alloc((size_t)NN * 128 * 2);
  __bf16* PHh = (__bf16*)alloc((size_t)NN * 256 * 2);     // h planes (<=256 cols)
  __bf16* PHl = (__bf16*)alloc((size_t)NN * 256 * 2);
  __bf16* Wt1h = (__bf16*)alloc(128 * 256 * 2); __bf16* Wt1l = (__bf16*)alloc(128 * 256 * 2);
  __bf16* Wt2h = (__bf16*)alloc(256 * 128 * 2); __bf16* Wt2l = (__bf16*)alloc(256 * 128 * 2);
  __bf16* Wt3h = (__bf16*)alloc(128 * 64 * 2);  __bf16* Wt3l = (__bf16*)alloc(128 * 64 * 2);
  __bf16* Wt4h = (__bf16*)alloc(64 * 6 * 2);    __bf16* Wt4l = (__bf16*)alloc(64 * 6 * 2);
  int* degi = (int*)alloc((size_t)NN * 4);
  float* dinv = (float*)alloc((size_t)NN * 4);
  int* rp = (int*)alloc((size_t)(NN + 1) * 4);
  int* cursor = (int*)alloc((size_t)NN * 4);
  int* incl = (int*)alloc((size_t)NN * 4);
  int* bsum = (int*)alloc(64 * 4);
  int* col = (int*)alloc((size_t)NE * 4);

  const int nBlkN = (NN + 255) / 256;
  const int nBlkE = (NE + 255) / 256;
  const int nBlkScan = (NN + 1023) / 1024;  // 49
  const int gM = (NN + 127) / 128;          // 391

  // degree + dinv
  memset_i32<<<nBlkN, 256, 0, stream>>>(degi, NN);
  deg_kernel<<<nBlkE, 256, 0, stream>>>(edst, degi, NE);
  dinv_kernel<<<nBlkN, 256, 0, stream>>>(degi, dinv, NN);

  // CSR build
  scan1<<<nBlkScan, 1024, 0, stream>>>(degi, incl, bsum, NN);
  scan2<<<1, 64, 0, stream>>>(bsum, nBlkScan);
  scan3<<<nBlkScan, 1024, 0, stream>>>(degi, incl, bsum, rp, cursor, NN);
  fill_kernel<<<nBlkE, 256, 0, stream>>>(esrc, edst, cursor, col, NE);

  // weight transpose+split
  wsplit<<<(128 * 256 + 255) / 256, 256, 0, stream>>>(W1, Wt1h, Wt1l, 128, 256);
  wsplit<<<(256 * 128 + 255) / 256, 256, 0, stream>>>(W2, Wt2h, Wt2l, 256, 128);
  wsplit<<<(128 * 64 + 255) / 256, 256, 0, stream>>>(W3, Wt3h, Wt3l, 128, 64);
  wsplit<<<(64 * 6 + 255) / 256, 256, 0, stream>>>(W4, Wt4h, Wt4l, 64, 6);

  // ---- layer 1: propagate (dim 128, prescale fused, D=8 control) then GEMM1 ----
  prop_kernel<128, 0, true, true><<<(NN + 3) / 4, 256, 0, stream>>>(
      x, rp, col, dinv, nullptr, nullptr, nullptr, nullptr, nullptr,
      nullptr, PAh, PAl, NN);
  {
    dim3 g(gM, 2);
    mfma_gemm<128, 0><<<g, 256, 0, stream>>>(PAh, PAl, Wt1h, Wt1l, b1, g1, be1, m1, v1,
                                             nullptr, nullptr, PHh, PHl, NN, 128, 256);
  }
  // ---- layer 2: GEMM2(*dinv -> f32) then propagate(+b2,BN2,ReLU -> hi/lo, D=16) ----
  {
    dim3 g(gM, 1);
    mfma_gemm<128, 1><<<g, 256, 0, stream>>>(PHh, PHl, Wt2h, Wt2l, nullptr, nullptr, nullptr,
                                             nullptr, nullptr, dinv, F1, nullptr, nullptr,
                                             NN, 256, 128);
  }
  prop_kernel<128, 1, true, false><<<(NN + 3) / 4, 256, 0, stream>>>(
      F1, rp, col, dinv, b2, g2, be2, m2, v2, nullptr, PAh, PAl, NN);
  // ---- layer 3: GEMM3(*dinv -> f32) then propagate(+b3,BN3,ReLU -> hi/lo, D=16) ----
  {
    dim3 g(gM, 1);
    mfma_gemm<64, 1><<<g, 256, 0, stream>>>(PAh, PAl, Wt3h, Wt3l, nullptr, nullptr, nullptr,
                                            nullptr, nullptr, dinv, F1, nullptr, nullptr,
                                            NN, 128, 64);
  }
  prop_kernel<64, 1, true, false><<<(NN + 3) / 4, 256, 0, stream>>>(
      F1, rp, col, dinv, b3, g3, be3, m3, v3, nullptr, PHh, PHl, NN);
  // ---- layer 4: GEMM4(*dinv -> f32, N=6) then propagate(+b4) ----
  {
    dim3 g(gM, 1);
    mfma_gemm<16, 1><<<g, 256, 0, stream>>>(PHh, PHl, Wt4h, Wt4l, nullptr, nullptr, nullptr,
                                            nullptr, nullptr, dinv, F1, nullptr, nullptr,
                                            NN, 64, 6);
  }
  prop_kernel<6, 2, false, false><<<(NN + 31) / 32, 256, 0, stream>>>(
      F1, rp, col, dinv, b4, nullptr, nullptr, nullptr, nullptr, out, nullptr, nullptr, NN);
}